// Round 6
// baseline (296.407 us; speedup 1.0000x reference)
//
#include <hip/hip_runtime.h>
#include <stdint.h>

// B=2, S=2048, D=768, H=12, hd=64
typedef float v4f __attribute__((ext_vector_type(4)));
typedef short v8s __attribute__((ext_vector_type(8)));

#define AS1 __attribute__((address_space(1)))
#define AS3 __attribute__((address_space(3)))

__device__ __forceinline__ void load16_to_lds(const void* g, void* l) {
  __builtin_amdgcn_global_load_lds((AS1 void*)g, (AS3 void*)l, 16, 0, 0);
}

__device__ __forceinline__ float fexp2(float x) {
#if __has_builtin(__builtin_amdgcn_exp2f)
  return __builtin_amdgcn_exp2f(x);
#else
  return exp2f(x);
#endif
}

// round-half-up fp32 -> bf16
__device__ __forceinline__ unsigned short f2bf_rn(float f) {
  union { float f; uint32_t u; } v; v.f = f;
  return (unsigned short)((v.u + 0x8000u) >> 16);
}
// pack two fp32 -> bf16x2 dword via v_perm (x in low half)
__device__ __forceinline__ uint32_t pack_bf2(float x, float y) {
  union { float f; uint32_t u; } a, b; a.f = x; b.f = y;
  return __builtin_amdgcn_perm(b.u + 0x8000u, a.u + 0x8000u, 0x07060302u);
}

#define QSCALE 0.052058786f  // log2(e)/sqrt(768), folded into Wq & bq

// ---------------------------------------------------------------------------
// Kernel 1: QKV GEMM with inline fp32->bf16 conversion of A and W during LDS
// staging (no separate convert kernel, no bf16 copies in HBM), plus mask-pack
// as a 4th z-slice. 128x128 tile, BK=32, dbuf, software-pipelined 2 tiles
// ahead. z=0: query*Wq(scaled)->Qb ; z=1: key*Wk->Kb ; z=2: value*Wv->Vt.
// For z=2 the MFMA operands are swapped (C rows = n) so Vt stores are
// contiguous 32B chunks instead of 8B scatters at 4KB stride.
// z=3: mask -> 1 bit/entry (192 grid-stride blocks).
// ---------------------------------------------------------------------------
__global__ __launch_bounds__(256, 3) void gemm_qkv_kernel(
    const float* __restrict__ qin, const float* __restrict__ kin,
    const float* __restrict__ vin,
    const float* __restrict__ Wq, const float* __restrict__ Wk,
    const float* __restrict__ Wv,
    const float* __restrict__ bq, const float* __restrict__ bk,
    const float* __restrict__ bv, const uint32_t* __restrict__ mask,
    unsigned short* __restrict__ Qb, unsigned short* __restrict__ Kb,
    unsigned short* __restrict__ Vt, uint32_t* __restrict__ bits) {
  const int tid = threadIdx.x;
  if (blockIdx.z == 3) {  // ---- mask pack ----
    __shared__ int s_i32;
    if (tid == 0) s_i32 = 1;
    __syncthreads();
    if (mask[tid] > 1u) s_i32 = 0;  // byte-mode detector (P(fail)=8^-256)
    __syncthreads();
    const int lane = tid & 63;
    for (int g = blockIdx.x + 32 * blockIdx.y; g < 1024; g += 192) {
      if (s_i32) {
        const int gw = (g * 256 + tid) >> 6;  // 0..4095
#pragma unroll 4
        for (int it2 = 0; it2 < 32; ++it2) {
          const size_t base = (size_t)gw * 2048 + it2 * 64;
          unsigned long long bal = __ballot(mask[base + lane] != 0u);
          if (lane == 0) *(unsigned long long*)&bits[base >> 5] = bal;
        }
      } else {
        const int wi = g * 256 + tid;
        const uint32_t* p = mask + (size_t)wi * 8;
        uint32_t w = 0;
#pragma unroll
        for (int j8 = 0; j8 < 8; ++j8) {
          uint32_t u = p[j8];
#pragma unroll
          for (int k = 0; k < 4; ++k)
            w |= (((u >> (8 * k)) & 0xFFu) ? 1u : 0u) << (j8 * 4 + k);
        }
        bits[wi] = w;
      }
    }
    return;
  }

  const int which = blockIdx.z;
  const float* A; const float* W; const float* bias; float wsc = 1.f;
  if (which == 0)      { A = qin; W = Wq; bias = bq; wsc = QSCALE; }
  else if (which == 1) { A = kin; W = Wk; bias = bk; }
  else                 { A = vin; W = Wv; bias = bv; }

  const int m0 = blockIdx.x * 128, n0 = blockIdx.y * 128;
  const int lane = tid & 63, wid = tid >> 6;
  const int wm = wid >> 1, wn = wid & 1;
  const int l16 = lane & 15, quad = lane >> 4;

  __shared__ __align__(16) unsigned short As[2][128 * 32];
  __shared__ __align__(16) unsigned short Bs[2][128 * 32];

  v4f acc[4][4];
#pragma unroll
  for (int i = 0; i < 4; ++i)
#pragma unroll
    for (int j = 0; j < 4; ++j) { v4f z = {0.f, 0.f, 0.f, 0.f}; acc[i][j] = z; }

  // staging geometry: unit u = 8 consecutive elems; c = tid + i*256 (i<2):
  // row = c>>2 (0..127), col8 = (c&3)*8  -> one b128 LDS write per unit.
  const float* pA[2]; const float* pW[2]; int offs[2];
#pragma unroll
  for (int i = 0; i < 2; ++i) {
    const int c = tid + i * 256;
    const int row = c >> 2, col8 = (c & 3) * 8;
    pA[i] = A + (size_t)(m0 + row) * 768 + col8;
    pW[i] = W + (size_t)(n0 + row) * 768 + col8;
    offs[i] = row * 32 + col8;
  }

  float4 fa[2][2], fw[2][2];
#define QKV_LOAD(k0)                                      \
  do {                                                    \
    _Pragma("unroll") for (int i = 0; i < 2; ++i) {       \
      fa[i][0] = *(const float4*)(pA[i] + (k0));          \
      fa[i][1] = *(const float4*)(pA[i] + (k0) + 4);      \
      fw[i][0] = *(const float4*)(pW[i] + (k0));          \
      fw[i][1] = *(const float4*)(pW[i] + (k0) + 4);      \
    }                                                     \
  } while (0)
#define QKV_STORE(buf)                                                   \
  do {                                                                   \
    _Pragma("unroll") for (int i = 0; i < 2; ++i) {                      \
      uint4 oa, ow;                                                      \
      oa.x = pack_bf2(fa[i][0].x, fa[i][0].y);                           \
      oa.y = pack_bf2(fa[i][0].z, fa[i][0].w);                           \
      oa.z = pack_bf2(fa[i][1].x, fa[i][1].y);                           \
      oa.w = pack_bf2(fa[i][1].z, fa[i][1].w);                           \
      ow.x = pack_bf2(fw[i][0].x * wsc, fw[i][0].y * wsc);               \
      ow.y = pack_bf2(fw[i][0].z * wsc, fw[i][0].w * wsc);               \
      ow.z = pack_bf2(fw[i][1].x * wsc, fw[i][1].y * wsc);               \
      ow.w = pack_bf2(fw[i][1].z * wsc, fw[i][1].w * wsc);               \
      *(uint4*)&As[buf][offs[i]] = oa;                                   \
      *(uint4*)&Bs[buf][offs[i]] = ow;                                   \
    }                                                                    \
  } while (0)

  QKV_LOAD(0);
  QKV_STORE(0);
  QKV_LOAD(32);
#pragma unroll 2
  for (int ks = 0; ks < 24; ++ks) {
    const int bufc = ks & 1;
    __syncthreads();
    // fragment reads; operand swap for which==2 (A-op <- W tile)
    v8s af[4], bf[4];
    const unsigned short* Abase = (which == 2) ? Bs[bufc] : As[bufc];
    const unsigned short* Bbase = (which == 2) ? As[bufc] : Bs[bufc];
#pragma unroll
    for (int i = 0; i < 4; ++i)
      af[i] = *(const v8s*)&Abase[(wm * 64 + i * 16 + l16) * 32 + quad * 8];
#pragma unroll
    for (int j = 0; j < 4; ++j)
      bf[j] = *(const v8s*)&Bbase[(wn * 64 + j * 16 + l16) * 32 + quad * 8];
    if (ks < 23) QKV_STORE(bufc ^ 1);
#pragma unroll
    for (int i = 0; i < 4; ++i)
#pragma unroll
      for (int j = 0; j < 4; ++j)
        acc[i][j] = __builtin_amdgcn_mfma_f32_16x16x32_bf16(af[i], bf[j],
                                                            acc[i][j], 0, 0, 0);
    if (ks < 22) QKV_LOAD((ks + 2) * 32);
  }
#undef QKV_LOAD
#undef QKV_STORE

  if (which == 2) {
    // acc rows = n (dim), cols = m (s): contiguous-ss stores
    const int bb = m0 >> 11;
#pragma unroll
    for (int i = 0; i < 4; ++i) {
#pragma unroll
      for (int j = 0; j < 4; ++j) {
        const int nbase = n0 + wm * 64 + i * 16 + quad * 4;
        const int mcol = m0 + wn * 64 + j * 16 + l16;
        const int ss = mcol & 2047;
#pragma unroll
        for (int r = 0; r < 4; ++r) {
          const int n = nbase + r;
          Vt[((size_t)bb * 768 + n) * 2048 + ss] =
              f2bf_rn(acc[i][j][r] + bias[n]);
        }
      }
    }
  } else {
    unsigned short* dst = (which == 0) ? Qb : Kb;
    const float bscale = (which == 0) ? QSCALE : 1.f;
#pragma unroll
    for (int i = 0; i < 4; ++i) {
#pragma unroll
      for (int j = 0; j < 4; ++j) {
        const int mbase = m0 + wm * 64 + i * 16 + quad * 4;
        const int n = n0 + wn * 64 + j * 16 + l16;
        const float bv_ = bias[n] * bscale;
#pragma unroll
        for (int r = 0; r < 4; ++r)
          dst[(size_t)(mbase + r) * 768 + n] = f2bf_rn(acc[i][j][r] + bv_);
      }
    }
  }
}

// ---------------------------------------------------------------------------
// Kernel 2: attention (unchanged from R5). S^T formulation, register mask,
// no-max exp2 softmax, ones-MFMA denominator, XOR-swizzled LDS, dbuf
// single-barrier prefetch. LDS 40960 B -> 4 blocks/CU. grid (32,12,2) x 256.
// ---------------------------------------------------------------------------
__global__ __launch_bounds__(256, 4) void attn_kernel(
    const unsigned short* __restrict__ Qb, const unsigned short* __restrict__ Kb,
    const unsigned short* __restrict__ Vt, const uint32_t* __restrict__ mbits,
    unsigned short* __restrict__ X) {
  const int q0 = blockIdx.x * 64;
  const int h = blockIdx.y, b = blockIdx.z;
  const int tid = threadIdx.x, w = tid >> 6, lane = tid & 63;
  const int l16 = lane & 15, quad = lane >> 4, l7 = l16 & 7;

  __shared__ __align__(16) unsigned short Kl[2][64 * 64];  // 16 KB [key][dim]
  __shared__ __align__(16) unsigned short Vl[2][64 * 64];  // 16 KB [dim][key]
  __shared__ __align__(16) unsigned short Pl[4][16 * 64];  //  8 KB [q][key]

  v8s aq[2];
  {
    const unsigned short* qp =
        Qb + (size_t)(b * 2048 + q0 + w * 16 + l16) * 768 + h * 64 + quad * 8;
    aq[0] = *(const v8s*)qp;
    aq[1] = *(const v8s*)(qp + 32);
  }

  v4f o[4], ol;
#pragma unroll
  for (int nt = 0; nt < 4; ++nt) { v4f z = {0.f, 0.f, 0.f, 0.f}; o[nt] = z; }
  { v4f z = {0.f, 0.f, 0.f, 0.f}; ol = z; }

  v8s bones;
  {
    const short v1 = (l16 == 0) ? (short)0x3F80 : (short)0;
#pragma unroll
    for (int j = 0; j < 8; ++j) bones[j] = v1;
  }

  const int rsub = lane >> 3;
  const int csub = ((lane & 7) ^ rsub) * 8;
  const unsigned short* kg0 = Kb + (size_t)(b * 2048 + w * 16) * 768 + h * 64;
  const unsigned short* vg0 = Vt + (size_t)(b * 768 + h * 64 + w * 16) * 2048;
  const uint2* mp =
      (const uint2*)(mbits + (size_t)(b * 2048 + q0 + w * 16 + l16) * 64);

#define ATTN_STAGE(kk0, buf)                                                   \
  do {                                                                         \
    const unsigned short* kg = kg0 + (size_t)(kk0) * 768;                      \
    const unsigned short* vg = vg0 + (kk0);                                    \
    load16_to_lds(kg + (size_t)rsub * 768 + csub, &Kl[buf][(w * 16) * 64]);    \
    load16_to_lds(kg + (size_t)(8 + rsub) * 768 + csub,                        \
                  &Kl[buf][(w * 16 + 8) * 64]);                                \
    load16_to_lds(vg + (size_t)rsub * 2048 + csub, &Vl[buf][(w * 16) * 64]);   \
    load16_to_lds(vg + (size_t)(8 + rsub) * 2048 + csub,                       \
                  &Vl[buf][(w * 16 + 8) * 64]);                                \
  } while (0)

  ATTN_STAGE(0, 0);
  uint2 mreg = mp[0];
#pragma unroll 2
  for (int it = 0; it < 32; ++it) {
    const int bufc = it & 1;
    __syncthreads();

    v8s bk[2][4];
#pragma unroll
    for (int kt = 0; kt < 2; ++kt)
#pragma unroll
      for (int nt = 0; nt < 4; ++nt)
        bk[kt][nt] = *(const v8s*)&Kl[bufc][(nt * 16 + l16) * 64 +
                                           (((kt * 4 + quad) ^ l7) << 3)];
    uint2 mnext;
    if (it < 31) {
      ATTN_STAGE((it + 1) * 64, bufc ^ 1);
      mnext = mp[it + 1];
    }

    v4f sacc[4];
#pragma unroll
    for (int nt = 0; nt < 4; ++nt) { v4f z = {0.f, 0.f, 0.f, 0.f}; sacc[nt] = z; }
#pragma unroll
    for (int kt = 0; kt < 2; ++kt)
#pragma unroll
      for (int nt = 0; nt < 4; ++nt)
        sacc[nt] = __builtin_amdgcn_mfma_f32_16x16x32_bf16(bk[kt][nt], aq[kt],
                                                           sacc[nt], 0, 0, 0);

    const uint32_t u[4] = {mreg.x >> (quad * 4), mreg.x >> (quad * 4 + 16),
                           mreg.y >> (quad * 4), mreg.y >> (quad * 4 + 16)};
#pragma unroll
    for (int nt = 0; nt < 4; ++nt) {
      const float p0 = (u[nt] & 1u) ? 0.f : fexp2(sacc[nt][0]);
      const float p1 = ((u[nt] >> 1) & 1u) ? 0.f : fexp2(sacc[nt][1]);
      const float p2 = ((u[nt] >> 2) & 1u) ? 0.f : fexp2(sacc[nt][2]);
      const float p3 = ((u[nt] >> 3) & 1u) ? 0.f : fexp2(sacc[nt][3]);
      uint2 pk;
      pk.x = pack_bf2(p0, p1);
      pk.y = pack_bf2(p2, p3);
      const int elem =
          l16 * 64 + (((nt * 2 + (quad >> 1)) ^ l7) << 3) + (quad & 1) * 4;
      *(uint2*)&Pl[w][elem] = pk;
    }

#pragma unroll
    for (int kt = 0; kt < 2; ++kt) {
      const v8s ap = *(const v8s*)&Pl[w][l16 * 64 + (((kt * 4 + quad) ^ l7) << 3)];
#pragma unroll
      for (int nt = 0; nt < 4; ++nt) {
        const v8s bv = *(const v8s*)&Vl[bufc][(nt * 16 + l16) * 64 +
                                             (((kt * 4 + quad) ^ l7) << 3)];
        o[nt] = __builtin_amdgcn_mfma_f32_16x16x32_bf16(ap, bv, o[nt], 0, 0, 0);
      }
      ol = __builtin_amdgcn_mfma_f32_16x16x32_bf16(ap, bones, ol, 0, 0, 0);
    }
    mreg = mnext;
  }
#undef ATTN_STAGE

  const int hb2 = 2 * h + b;
  const int b2 = (hb2 >= 12) ? 1 : 0;
  const int h2 = hb2 - 12 * b2;
#pragma unroll
  for (int r = 0; r < 4; ++r) {
    const float lsum = __shfl(ol[r], quad * 16, 64);
    const float inv_l = 1.f / lsum;
    const int q = q0 + w * 16 + quad * 4 + r;
#pragma unroll
    for (int nt = 0; nt < 4; ++nt) {
      const int d = nt * 16 + l16;
      const size_t f = (size_t)h2 * 262144 + (size_t)q * 128 + b2 * 64 + d;
      X[f] = f2bf_rn(o[nt][r] * inv_l);
    }
  }
}

// ---------------------------------------------------------------------------
// Kernel 3: out = X(bf16) @ Wc^T + bc + query. Wc fp32 inline-converted
// during staging; X staged via global_load_lds. 64x128 tile, dbuf. grid (64,6).
// ---------------------------------------------------------------------------
__global__ __launch_bounds__(256, 3) void gemm2_kernel(
    const unsigned short* __restrict__ X, const float* __restrict__ Wc,
    const float* __restrict__ bc, const float* __restrict__ query,
    float* __restrict__ out) {
  const int m0 = blockIdx.x * 64, n0 = blockIdx.y * 128;
  const int tid = threadIdx.x, lane = tid & 63, wid = tid >> 6;
  const int wm = wid >> 1, wn = wid & 1;
  const int l16 = lane & 15, quad = lane >> 4;

  __shared__ __align__(16) unsigned short As[2][64 * 32];
  __shared__ __align__(16) unsigned short Bs[2][128 * 32];

  v4f acc[2][4];
#pragma unroll
  for (int i = 0; i < 2; ++i)
#pragma unroll
    for (int j = 0; j < 4; ++j) { v4f z = {0.f, 0.f, 0.f, 0.f}; acc[i][j] = z; }

  // A DMA: 1 chunk/thread
  const unsigned short* a0 = X + (size_t)(m0 + (tid >> 2)) * 768 + (tid & 3) * 8;
  // B convert: units c = tid + i*256 (i<2): row=c>>2, col8=(c&3)*8
  const float* pW[2]; int offs[2];
#pragma unroll
  for (int i = 0; i < 2; ++i) {
    const int c = tid + i * 256;
    const int row = c >> 2, col8 = (c & 3) * 8;
    pW[i] = Wc + (size_t)(n0 + row) * 768 + col8;
    offs[i] = row * 32 + col8;
  }

  float4 fw[2][2];
#define G2_LOAD(k0)                                       \
  do {                                                    \
    _Pragma("unroll") for (int i = 0; i < 2; ++i) {       \
      fw[i][0] = *(const float4*)(pW[i] + (k0));          \
      fw[i][1] = *(const float4*)(pW[i] + (k0) + 4);      \
    }                                                     \
  } while (0)
#define G2_STORE(buf)                                                    \
  do {                                                                   \
    _Pragma("unroll") for (int i = 0; i < 2; ++i) {                      \
      uint4 ow;                                                          \
      ow.x = pack_bf2(fw[i][0].x, fw[i][0].y);                           \
      ow.y = pack_bf2(fw[i][0].z, fw[i][0].w);                           \
      ow.z = pack_bf2(fw[i][1].x, fw[i][1].y);                           \
      ow.w = pack_bf2(fw[i][1].z, fw[i][1].w);                           \
      *(uint4*)&Bs[buf][offs[i]] = ow;                                   \
    }                                                                    \
  } while (0)

  G2_LOAD(0);
  G2_STORE(0);
  load16_to_lds(a0, &As[0][(wid * 64) * 8]);
  G2_LOAD(32);
#pragma unroll 2
  for (int ks = 0; ks < 24; ++ks) {
    const int bufc = ks & 1;
    __syncthreads();
    v8s af[2], bf[4];
#pragma unroll
    for (int i = 0; i < 2; ++i)
      af[i] = *(const v8s*)&As[bufc][(wm * 32 + i * 16 + l16) * 32 + quad * 8];
#pragma unroll
    for (int j = 0; j < 4; ++j)
      bf[j] = *(const v8s*)&Bs[bufc][(wn * 64 + j * 16 + l16) * 32 + quad * 8];
    if (ks < 23) {
      G2_STORE(bufc ^ 1);
      load16_to_lds(a0 + (ks + 1) * 32, &As[bufc ^ 1][(wid * 64) * 8]);
    }
#pragma unroll
    for (int i = 0; i < 2; ++i)
#pragma unroll
      for (int j = 0; j < 4; ++j)
        acc[i][j] = __builtin_amdgcn_mfma_f32_16x16x32_bf16(af[i], bf[j],
                                                            acc[i][j], 0, 0, 0);
    if (ks < 22) G2_LOAD((ks + 2) * 32);
  }
#undef G2_LOAD
#undef G2_STORE

#pragma unroll
  for (int i = 0; i < 2; ++i) {
#pragma unroll
    for (int j = 0; j < 4; ++j) {
      const int mbase = m0 + wm * 32 + i * 16 + quad * 4;
      const int n = n0 + wn * 64 + j * 16 + l16;
      const float bv_ = bc[n];
#pragma unroll
      for (int r = 0; r < 4; ++r) {
        const int m = mbase + r;
        out[(size_t)m * 768 + n] =
            acc[i][j][r] + bv_ + query[(size_t)m * 768 + n];
      }
    }
  }
}

// ---------------------------------------------------------------------------
// Kernel 4: LayerNorm in place. One block per row.
// ---------------------------------------------------------------------------
__global__ __launch_bounds__(256) void ln_kernel(float* __restrict__ out,
                                                 const float* __restrict__ g,
                                                 const float* __restrict__ bta) {
  const int row = blockIdx.x;
  const int tid = threadIdx.x;
  float x[3];
  float s = 0.f, sq = 0.f;
#pragma unroll
  for (int k = 0; k < 3; ++k) {
    x[k] = out[(size_t)row * 768 + tid + k * 256];
    s += x[k];
    sq += x[k] * x[k];
  }
#pragma unroll
  for (int off = 1; off < 64; off <<= 1) {
    s += __shfl_xor(s, off, 64);
    sq += __shfl_xor(sq, off, 64);
  }
  __shared__ float ss[4], ssq[4];
  const int w = tid >> 6, lane = tid & 63;
  if (lane == 0) { ss[w] = s; ssq[w] = sq; }
  __syncthreads();
  s = ss[0] + ss[1] + ss[2] + ss[3];
  sq = ssq[0] + ssq[1] + ssq[2] + ssq[3];
  const float mu = s * (1.f / 768.f);
  const float var = sq * (1.f / 768.f) - mu * mu;
  const float rstd = rsqrtf(var + 1e-5f);
#pragma unroll
  for (int k = 0; k < 3; ++k) {
    const int cc = tid + k * 256;
    out[(size_t)row * 768 + cc] = g[cc] * (x[k] - mu) * rstd + bta[cc];
  }
}

// ---------------------------------------------------------------------------
extern "C" void kernel_launch(void* const* d_in, const int* in_sizes, int n_in,
                              void* d_out, int out_size, void* d_ws,
                              size_t ws_size, hipStream_t stream) {
  const float* key   = (const float*)d_in[0];
  const float* query = (const float*)d_in[1];
  const float* value = (const float*)d_in[2];
  const uint32_t* mask = (const uint32_t*)d_in[3];
  const float* Wk = (const float*)d_in[4];
  const float* bk = (const float*)d_in[5];
  const float* Wq = (const float*)d_in[6];
  const float* bq = (const float*)d_in[7];
  const float* Wv = (const float*)d_in[8];
  const float* bv = (const float*)d_in[9];
  const float* Wc = (const float*)d_in[10];
  const float* bc = (const float*)d_in[11];
  const float* lng = (const float*)d_in[12];
  const float* lnb = (const float*)d_in[13];

  char* ws = (char*)d_ws;
  uint32_t*       mbits = (uint32_t*)(ws);                 // 1 MB
  unsigned short* Qb = (unsigned short*)(ws + 0x100000);   // 6 MB each
  unsigned short* Kb = (unsigned short*)(ws + 0x700000);
  unsigned short* Vt = (unsigned short*)(ws + 0xD00000);
  unsigned short* X  = (unsigned short*)(ws + 0x1300000);  // end 25 MB
  float* out = (float*)d_out;

  gemm_qkv_kernel<<<dim3(32, 6, 4), dim3(256), 0, stream>>>(
      query, key, value, Wq, Wk, Wv, bq, bk, bv, mask, Qb, Kb, Vt, mbits);
  attn_kernel<<<dim3(32, 12, 2), dim3(256), 0, stream>>>(Qb, Kb, Vt, mbits, X);
  gemm2_kernel<<<dim3(64, 6), dim3(256), 0, stream>>>(X, Wc, bc, query, out);
  ln_kernel<<<dim3(4096), dim3(256), 0, stream>>>(out, lng, lnb);
}

// Round 7
// 240.087 us; speedup vs baseline: 1.2346x; 1.2346x over previous
//
#include <hip/hip_runtime.h>
#include <stdint.h>

// B=2, S=2048, D=768, H=12, hd=64
typedef float v4f __attribute__((ext_vector_type(4)));
typedef short v8s __attribute__((ext_vector_type(8)));

#define AS1 __attribute__((address_space(1)))
#define AS3 __attribute__((address_space(3)))

__device__ __forceinline__ void load16_to_lds(const void* g, void* l) {
  __builtin_amdgcn_global_load_lds((AS1 void*)g, (AS3 void*)l, 16, 0, 0);
}

__device__ __forceinline__ float fexp2(float x) {
#if __has_builtin(__builtin_amdgcn_exp2f)
  return __builtin_amdgcn_exp2f(x);
#else
  return exp2f(x);
#endif
}

// round-half-up fp32 -> bf16
__device__ __forceinline__ unsigned short f2bf_rn(float f) {
  union { float f; uint32_t u; } v; v.f = f;
  return (unsigned short)((v.u + 0x8000u) >> 16);
}
// pack two fp32 -> bf16x2 dword via v_perm (x in low half)
__device__ __forceinline__ uint32_t pack_bf2(float x, float y) {
  union { float f; uint32_t u; } a, b; a.f = x; b.f = y;
  return __builtin_amdgcn_perm(b.u + 0x8000u, a.u + 0x8000u, 0x07060302u);
}

#define QSCALE 0.052058786f  // log2(e)/sqrt(768), folded into Wq & bq

// ---------------------------------------------------------------------------
// Kernel 1: fused convert + mask pack, compact 1-D grid (12544 blocks):
//   [0,2304)      weights fp32->bf16 (576 blocks each; Wq scaled by QSCALE)
//   [2304,11520)  inputs fp32->bf16 (3072 blocks each)
//   [11520,12544) mask -> 1 bit/entry
// ---------------------------------------------------------------------------
__global__ __launch_bounds__(256) void conv_pack_kernel(
    const float* __restrict__ wk, const float* __restrict__ wq,
    const float* __restrict__ wv, const float* __restrict__ wc,
    const float* __restrict__ kin, const float* __restrict__ qin,
    const float* __restrict__ vin, const uint32_t* __restrict__ mask,
    unsigned short* __restrict__ dk, unsigned short* __restrict__ dq,
    unsigned short* __restrict__ dv, unsigned short* __restrict__ dc,
    unsigned short* __restrict__ dki, unsigned short* __restrict__ dqi,
    unsigned short* __restrict__ dvi, uint32_t* __restrict__ bits) {
  const int id = blockIdx.x;
  const int tid = threadIdx.x;
  if (id >= 11520) {  // mask pack
    const int xx = id - 11520;
    __shared__ int s_i32;
    if (tid == 0) s_i32 = 1;
    __syncthreads();
    if (mask[tid] > 1u) s_i32 = 0;  // byte-mode detector (P(fail)=8^-256)
    __syncthreads();
    if (s_i32) {
      const int lane = tid & 63;
      const int gw = (xx * 256 + tid) >> 6;  // 0..4095
#pragma unroll 4
      for (int it = 0; it < 32; ++it) {
        const size_t base = (size_t)gw * 2048 + it * 64;
        unsigned long long bal = __ballot(mask[base + lane] != 0u);
        if (lane == 0) *(unsigned long long*)&bits[base >> 5] = bal;
      }
    } else {
      const int wi = xx * 256 + tid;
      const uint32_t* p = mask + (size_t)wi * 8;
      uint32_t w = 0;
#pragma unroll
      for (int j8 = 0; j8 < 8; ++j8) {
        uint32_t u = p[j8];
#pragma unroll
        for (int k = 0; k < 4; ++k)
          w |= (((u >> (8 * k)) & 0xFFu) ? 1u : 0u) << (j8 * 4 + k);
      }
      bits[wi] = w;
    }
    return;
  }
  const float* s; unsigned short* d; float sc = 1.f; int x;
  if (id < 2304) {
    const int y = id / 576;
    x = id - y * 576;
    if (y == 0)      { s = wk; d = dk; }
    else if (y == 1) { s = wq; d = dq; sc = QSCALE; }
    else if (y == 2) { s = wv; d = dv; }
    else             { s = wc; d = dc; }
  } else {
    const int t = id - 2304;
    const int y = t / 3072;
    x = t - y * 3072;
    if (y == 0)      { s = kin; d = dki; }
    else if (y == 1) { s = qin; d = dqi; }
    else             { s = vin; d = dvi; }
  }
  const int i = x * 256 + tid;
  float4 f = ((const float4*)s)[i];
  uint2 o;
  o.x = pack_bf2(f.x * sc, f.y * sc);
  o.y = pack_bf2(f.z * sc, f.w * sc);
  ((uint2*)d)[i] = o;
}

// ---------------------------------------------------------------------------
// Kernel 2: QKV GEMM, all-bf16, global_load_lds staging, dbuf single-barrier.
// 128x128 tile, BK=32, 4 waves 4x4 MFMA.
// z=0: Qin*Wq(scaled) -> Qb ; z=1: Kin*Wk -> Kb ; z=2: Vin*Wv -> Vt (transposed)
// ---------------------------------------------------------------------------
__global__ __launch_bounds__(256, 3) void gemm_qkv_kernel(
    const unsigned short* __restrict__ qin, const unsigned short* __restrict__ kin,
    const unsigned short* __restrict__ vin,
    const unsigned short* __restrict__ wqb, const unsigned short* __restrict__ wkb,
    const unsigned short* __restrict__ wvb,
    const float* __restrict__ bq, const float* __restrict__ bk,
    const float* __restrict__ bv,
    unsigned short* __restrict__ Qb, unsigned short* __restrict__ Kb,
    unsigned short* __restrict__ Vt) {
  const int which = blockIdx.z;
  const unsigned short* A; const unsigned short* Wb; const float* bias;
  float bscale = 1.f;
  if (which == 0)      { A = qin; Wb = wqb; bias = bq; bscale = QSCALE; }
  else if (which == 1) { A = kin; Wb = wkb; bias = bk; }
  else                 { A = vin; Wb = wvb; bias = bv; }

  const int m0 = blockIdx.x * 128, n0 = blockIdx.y * 128;
  const int tid = threadIdx.x, lane = tid & 63, wid = tid >> 6;
  const int wm = wid >> 1, wn = wid & 1;
  const int l16 = lane & 15, quad = lane >> 4;

  __shared__ __align__(16) unsigned short As[2][128 * 32];
  __shared__ __align__(16) unsigned short Bs[2][128 * 32];

  v4f acc[4][4];
#pragma unroll
  for (int i = 0; i < 4; ++i)
#pragma unroll
    for (int j = 0; j < 4; ++j) { v4f z = {0.f, 0.f, 0.f, 0.f}; acc[i][j] = z; }

  const int c0 = wid * 128 + lane, c1 = wid * 128 + 64 + lane;
  const unsigned short* a0 = A + (size_t)(m0 + (c0 >> 2)) * 768 + (c0 & 3) * 8;
  const unsigned short* a1 = A + (size_t)(m0 + (c1 >> 2)) * 768 + (c1 & 3) * 8;
  const unsigned short* b0 = Wb + (size_t)(n0 + (c0 >> 2)) * 768 + (c0 & 3) * 8;
  const unsigned short* b1 = Wb + (size_t)(n0 + (c1 >> 2)) * 768 + (c1 & 3) * 8;

#define QKV_STAGE(k0, buf)                                         \
  do {                                                             \
    load16_to_lds(a0 + (k0), &As[buf][(wid * 128) * 8]);           \
    load16_to_lds(a1 + (k0), &As[buf][(wid * 128 + 64) * 8]);      \
    load16_to_lds(b0 + (k0), &Bs[buf][(wid * 128) * 8]);           \
    load16_to_lds(b1 + (k0), &Bs[buf][(wid * 128 + 64) * 8]);      \
  } while (0)

  QKV_STAGE(0, 0);
#pragma unroll 2
  for (int ks = 0; ks < 24; ++ks) {
    const int bufc = ks & 1;
    __syncthreads();
    v8s af[4], bf[4];
#pragma unroll
    for (int i = 0; i < 4; ++i)
      af[i] = *(const v8s*)&As[bufc][(wm * 64 + i * 16 + l16) * 32 + quad * 8];
#pragma unroll
    for (int j = 0; j < 4; ++j)
      bf[j] = *(const v8s*)&Bs[bufc][(wn * 64 + j * 16 + l16) * 32 + quad * 8];
    if (ks < 23) QKV_STAGE((ks + 1) * 32, bufc ^ 1);
#pragma unroll
    for (int i = 0; i < 4; ++i)
#pragma unroll
      for (int j = 0; j < 4; ++j)
        acc[i][j] = __builtin_amdgcn_mfma_f32_16x16x32_bf16(af[i], bf[j],
                                                            acc[i][j], 0, 0, 0);
  }
#undef QKV_STAGE

#pragma unroll
  for (int i = 0; i < 4; ++i) {
#pragma unroll
    for (int j = 0; j < 4; ++j) {
      const int mbase = m0 + wm * 64 + i * 16 + quad * 4;
      const int n = n0 + wn * 64 + j * 16 + l16;
      const float bv_ = bias[n] * bscale;
      if (which == 2) {
        const int bb = mbase >> 11, ss = mbase & 2047;
        uint2 pk;
        pk.x = pack_bf2(acc[i][j][0] + bv_, acc[i][j][1] + bv_);
        pk.y = pack_bf2(acc[i][j][2] + bv_, acc[i][j][3] + bv_);
        *(uint2*)&Vt[((size_t)bb * 768 + n) * 2048 + ss] = pk;
      } else {
        unsigned short* dst = (which == 0) ? Qb : Kb;
#pragma unroll
        for (int r = 0; r < 4; ++r)
          dst[(size_t)(mbase + r) * 768 + n] = f2bf_rn(acc[i][j][r] + bv_);
      }
    }
  }
}

// ---------------------------------------------------------------------------
// Kernel 3: attention (R5 structure) with XCD-pinned block order: 1-D grid
// of 768, hb = id % 24 -> all 32 q-tiles of one (h,b) share id%8, i.e. land
// on one XCD; its 1.5 MB of K/V slices stay L2-resident (FETCH_SIZE drop).
// S^T formulation, register mask, no-max exp2 softmax, ones-MFMA denominator,
// XOR-swizzled LDS, dbuf single-barrier prefetch. LDS 40960 B -> 4 blocks/CU.
// ---------------------------------------------------------------------------
__global__ __launch_bounds__(256, 4) void attn_kernel(
    const unsigned short* __restrict__ Qb, const unsigned short* __restrict__ Kb,
    const unsigned short* __restrict__ Vt, const uint32_t* __restrict__ mbits,
    unsigned short* __restrict__ X) {
  const int id = blockIdx.x;
  const int hb = id % 24;           // XCD = id%8 = hb%8 (heuristic, speed-only)
  const int q0 = (id / 24) * 64;
  const int h = hb >> 1, b = hb & 1;
  const int tid = threadIdx.x, w = tid >> 6, lane = tid & 63;
  const int l16 = lane & 15, quad = lane >> 4, l7 = l16 & 7;

  __shared__ __align__(16) unsigned short Kl[2][64 * 64];  // 16 KB [key][dim]
  __shared__ __align__(16) unsigned short Vl[2][64 * 64];  // 16 KB [dim][key]
  __shared__ __align__(16) unsigned short Pl[4][16 * 64];  //  8 KB [q][key]

  v8s aq[2];
  {
    const unsigned short* qp =
        Qb + (size_t)(b * 2048 + q0 + w * 16 + l16) * 768 + h * 64 + quad * 8;
    aq[0] = *(const v8s*)qp;
    aq[1] = *(const v8s*)(qp + 32);
  }

  v4f o[4], ol;
#pragma unroll
  for (int nt = 0; nt < 4; ++nt) { v4f z = {0.f, 0.f, 0.f, 0.f}; o[nt] = z; }
  { v4f z = {0.f, 0.f, 0.f, 0.f}; ol = z; }

  v8s bones;
  {
    const short v1 = (l16 == 0) ? (short)0x3F80 : (short)0;
#pragma unroll
    for (int j = 0; j < 8; ++j) bones[j] = v1;
  }

  const int rsub = lane >> 3;
  const int csub = ((lane & 7) ^ rsub) * 8;
  const unsigned short* kg0 = Kb + (size_t)(b * 2048 + w * 16) * 768 + h * 64;
  const unsigned short* vg0 = Vt + (size_t)(b * 768 + h * 64 + w * 16) * 2048;
  const uint2* mp =
      (const uint2*)(mbits + (size_t)(b * 2048 + q0 + w * 16 + l16) * 64);

#define ATTN_STAGE(kk0, buf)                                                   \
  do {                                                                         \
    const unsigned short* kg = kg0 + (size_t)(kk0) * 768;                      \
    const unsigned short* vg = vg0 + (kk0);                                    \
    load16_to_lds(kg + (size_t)rsub * 768 + csub, &Kl[buf][(w * 16) * 64]);    \
    load16_to_lds(kg + (size_t)(8 + rsub) * 768 + csub,                        \
                  &Kl[buf][(w * 16 + 8) * 64]);                                \
    load16_to_lds(vg + (size_t)rsub * 2048 + csub, &Vl[buf][(w * 16) * 64]);   \
    load16_to_lds(vg + (size_t)(8 + rsub) * 2048 + csub,                       \
                  &Vl[buf][(w * 16 + 8) * 64]);                                \
  } while (0)

  ATTN_STAGE(0, 0);
  uint2 mreg = mp[0];
#pragma unroll 2
  for (int it = 0; it < 32; ++it) {
    const int bufc = it & 1;
    __syncthreads();

    v8s bk[2][4];
#pragma unroll
    for (int kt = 0; kt < 2; ++kt)
#pragma unroll
      for (int nt = 0; nt < 4; ++nt)
        bk[kt][nt] = *(const v8s*)&Kl[bufc][(nt * 16 + l16) * 64 +
                                           (((kt * 4 + quad) ^ l7) << 3)];
    uint2 mnext;
    if (it < 31) {
      ATTN_STAGE((it + 1) * 64, bufc ^ 1);
      mnext = mp[it + 1];
    }

    v4f sacc[4];
#pragma unroll
    for (int nt = 0; nt < 4; ++nt) { v4f z = {0.f, 0.f, 0.f, 0.f}; sacc[nt] = z; }
#pragma unroll
    for (int kt = 0; kt < 2; ++kt)
#pragma unroll
      for (int nt = 0; nt < 4; ++nt)
        sacc[nt] = __builtin_amdgcn_mfma_f32_16x16x32_bf16(bk[kt][nt], aq[kt],
                                                           sacc[nt], 0, 0, 0);

    const uint32_t u[4] = {mreg.x >> (quad * 4), mreg.x >> (quad * 4 + 16),
                           mreg.y >> (quad * 4), mreg.y >> (quad * 4 + 16)};
#pragma unroll
    for (int nt = 0; nt < 4; ++nt) {
      const float p0 = (u[nt] & 1u) ? 0.f : fexp2(sacc[nt][0]);
      const float p1 = ((u[nt] >> 1) & 1u) ? 0.f : fexp2(sacc[nt][1]);
      const float p2 = ((u[nt] >> 2) & 1u) ? 0.f : fexp2(sacc[nt][2]);
      const float p3 = ((u[nt] >> 3) & 1u) ? 0.f : fexp2(sacc[nt][3]);
      uint2 pk;
      pk.x = pack_bf2(p0, p1);
      pk.y = pack_bf2(p2, p3);
      const int elem =
          l16 * 64 + (((nt * 2 + (quad >> 1)) ^ l7) << 3) + (quad & 1) * 4;
      *(uint2*)&Pl[w][elem] = pk;
    }

#pragma unroll
    for (int kt = 0; kt < 2; ++kt) {
      const v8s ap = *(const v8s*)&Pl[w][l16 * 64 + (((kt * 4 + quad) ^ l7) << 3)];
#pragma unroll
      for (int nt = 0; nt < 4; ++nt) {
        const v8s bv = *(const v8s*)&Vl[bufc][(nt * 16 + l16) * 64 +
                                             (((kt * 4 + quad) ^ l7) << 3)];
        o[nt] = __builtin_amdgcn_mfma_f32_16x16x32_bf16(ap, bv, o[nt], 0, 0, 0);
      }
      ol = __builtin_amdgcn_mfma_f32_16x16x32_bf16(ap, bones, ol, 0, 0, 0);
    }
    mreg = mnext;
  }
#undef ATTN_STAGE

  const int hb2 = 2 * h + b;
  const int b2 = (hb2 >= 12) ? 1 : 0;
  const int h2 = hb2 - 12 * b2;
#pragma unroll
  for (int r = 0; r < 4; ++r) {
    const float lsum = __shfl(ol[r], quad * 16, 64);
    const float inv_l = 1.f / lsum;
    const int q = q0 + w * 16 + quad * 4 + r;
#pragma unroll
    for (int nt = 0; nt < 4; ++nt) {
      const int d = nt * 16 + l16;
      const size_t f = (size_t)h2 * 262144 + (size_t)q * 128 + b2 * 64 + d;
      X[f] = f2bf_rn(o[nt][r] * inv_l);
    }
  }
}

// ---------------------------------------------------------------------------
// Kernel 4: out = X(bf16) @ Wc^T(bf16) + bc + query. 64x128 tile, dbuf
// prefetch loop. grid (64, 6).
// ---------------------------------------------------------------------------
__global__ __launch_bounds__(256, 3) void gemm2_kernel(
    const unsigned short* __restrict__ X, const unsigned short* __restrict__ Wcb,
    const float* __restrict__ bc, const float* __restrict__ query,
    float* __restrict__ out) {
  const int m0 = blockIdx.x * 64, n0 = blockIdx.y * 128;
  const int tid = threadIdx.x, lane = tid & 63, wid = tid >> 6;
  const int wm = wid >> 1, wn = wid & 1;
  const int l16 = lane & 15, quad = lane >> 4;

  __shared__ __align__(16) unsigned short As[2][64 * 32];
  __shared__ __align__(16) unsigned short Bs[2][128 * 32];

  v4f acc[2][4];
#pragma unroll
  for (int i = 0; i < 2; ++i)
#pragma unroll
    for (int j = 0; j < 4; ++j) { v4f z = {0.f, 0.f, 0.f, 0.f}; acc[i][j] = z; }

  const int ca = tid;  // A chunk
  const unsigned short* a0 = X + (size_t)(m0 + (ca >> 2)) * 768 + (ca & 3) * 8;
  const int c0 = wid * 128 + lane, c1 = wid * 128 + 64 + lane;
  const unsigned short* b0 = Wcb + (size_t)(n0 + (c0 >> 2)) * 768 + (c0 & 3) * 8;
  const unsigned short* b1 = Wcb + (size_t)(n0 + (c1 >> 2)) * 768 + (c1 & 3) * 8;

#define G2_STAGE(k0, buf)                                        \
  do {                                                           \
    load16_to_lds(a0 + (k0), &As[buf][(wid * 64) * 8]);          \
    load16_to_lds(b0 + (k0), &Bs[buf][(wid * 128) * 8]);         \
    load16_to_lds(b1 + (k0), &Bs[buf][(wid * 128 + 64) * 8]);    \
  } while (0)

  G2_STAGE(0, 0);
#pragma unroll 2
  for (int ks = 0; ks < 24; ++ks) {
    const int bufc = ks & 1;
    __syncthreads();
    v8s af[2], bf[4];
#pragma unroll
    for (int i = 0; i < 2; ++i)
      af[i] = *(const v8s*)&As[bufc][(wm * 32 + i * 16 + l16) * 32 + quad * 8];
#pragma unroll
    for (int j = 0; j < 4; ++j)
      bf[j] = *(const v8s*)&Bs[bufc][(wn * 64 + j * 16 + l16) * 32 + quad * 8];
    if (ks < 23) G2_STAGE((ks + 1) * 32, bufc ^ 1);
#pragma unroll
    for (int i = 0; i < 2; ++i)
#pragma unroll
      for (int j = 0; j < 4; ++j)
        acc[i][j] = __builtin_amdgcn_mfma_f32_16x16x32_bf16(af[i], bf[j],
                                                            acc[i][j], 0, 0, 0);
  }
#undef G2_STAGE

#pragma unroll
  for (int i = 0; i < 2; ++i) {
#pragma unroll
    for (int j = 0; j < 4; ++j) {
      const int mbase = m0 + wm * 32 + i * 16 + quad * 4;
      const int n = n0 + wn * 64 + j * 16 + l16;
      const float bv_ = bc[n];
#pragma unroll
      for (int r = 0; r < 4; ++r) {
        const int m = mbase + r;
        out[(size_t)m * 768 + n] =
            acc[i][j][r] + bv_ + query[(size_t)m * 768 + n];
      }
    }
  }
}

// ---------------------------------------------------------------------------
// Kernel 5: LayerNorm in place. 4 rows per block (one wave per row), wave-only
// shuffle reduction, no barriers, float4 x3 per lane. grid 1024.
// ---------------------------------------------------------------------------
__global__ __launch_bounds__(256) void ln_kernel(float* __restrict__ out,
                                                 const float* __restrict__ g,
                                                 const float* __restrict__ bta) {
  const int row = blockIdx.x * 4 + (threadIdx.x >> 6);
  const int lane = threadIdx.x & 63;
  float* p = out + (size_t)row * 768 + lane * 12;
  float4 x0 = *(const float4*)(p);
  float4 x1 = *(const float4*)(p + 4);
  float4 x2 = *(const float4*)(p + 8);
  float s = (x0.x + x0.y + x0.z + x0.w) + (x1.x + x1.y + x1.z + x1.w) +
            (x2.x + x2.y + x2.z + x2.w);
  float sq = (x0.x * x0.x + x0.y * x0.y + x0.z * x0.z + x0.w * x0.w) +
             (x1.x * x1.x + x1.y * x1.y + x1.z * x1.z + x1.w * x1.w) +
             (x2.x * x2.x + x2.y * x2.y + x2.z * x2.z + x2.w * x2.w);
#pragma unroll
  for (int off = 1; off < 64; off <<= 1) {
    s += __shfl_xor(s, off, 64);
    sq += __shfl_xor(sq, off, 64);
  }
  const float mu = s * (1.f / 768.f);
  const float var = sq * (1.f / 768.f) - mu * mu;
  const float rstd = rsqrtf(var + 1e-5f);
  const float4 g0 = *(const float4*)(g + lane * 12);
  const float4 g1 = *(const float4*)(g + lane * 12 + 4);
  const float4 g2 = *(const float4*)(g + lane * 12 + 8);
  const float4 b0 = *(const float4*)(bta + lane * 12);
  const float4 b1 = *(const float4*)(bta + lane * 12 + 4);
  const float4 b2 = *(const float4*)(bta + lane * 12 + 8);
  float4 y0, y1, y2;
  y0.x = g0.x * (x0.x - mu) * rstd + b0.x;
  y0.y = g0.y * (x0.y - mu) * rstd + b0.y;
  y0.z = g0.z * (x0.z - mu) * rstd + b0.z;
  y0.w = g0.w * (x0.w - mu) * rstd + b0.w;
  y1.x = g1.x * (x1.x - mu) * rstd + b1.x;
  y1.y = g1.y * (x1.y - mu) * rstd + b1.y;
  y1.z = g1.z * (x1.z - mu) * rstd + b1.z;
  y1.w = g1.w * (x1.w - mu) * rstd + b1.w;
  y2.x = g2.x * (x2.x - mu) * rstd + b2.x;
  y2.y = g2.y * (x2.y - mu) * rstd + b2.y;
  y2.z = g2.z * (x2.z - mu) * rstd + b2.z;
  y2.w = g2.w * (x2.w - mu) * rstd + b2.w;
  *(float4*)(p) = y0;
  *(float4*)(p + 4) = y1;
  *(float4*)(p + 8) = y2;
}

// ---------------------------------------------------------------------------
extern "C" void kernel_launch(void* const* d_in, const int* in_sizes, int n_in,
                              void* d_out, int out_size, void* d_ws,
                              size_t ws_size, hipStream_t stream) {
  const float* key   = (const float*)d_in[0];
  const float* query = (const float*)d_in[1];
  const float* value = (const float*)d_in[2];
  const uint32_t* mask = (const uint32_t*)d_in[3];
  const float* Wk = (const float*)d_in[4];
  const float* bk = (const float*)d_in[5];
  const float* Wq = (const float*)d_in[6];
  const float* bq = (const float*)d_in[7];
  const float* Wv = (const float*)d_in[8];
  const float* bv = (const float*)d_in[9];
  const float* Wc = (const float*)d_in[10];
  const float* bc = (const float*)d_in[11];
  const float* lng = (const float*)d_in[12];
  const float* lnb = (const float*)d_in[13];

  char* ws = (char*)d_ws;
  uint32_t*       mbits = (uint32_t*)(ws);                   // 1 MB
  unsigned short* Wkb = (unsigned short*)(ws + 0x100000);    // 1.125 MB each
  unsigned short* Wqb = (unsigned short*)(ws + 0x220000);
  unsigned short* Wvb = (unsigned short*)(ws + 0x340000);
  unsigned short* Wcb = (unsigned short*)(ws + 0x460000);
  unsigned short* Qb  = (unsigned short*)(ws + 0x600000);    // 6 MB each
  unsigned short* Kb  = (unsigned short*)(ws + 0xC00000);
  unsigned short* Vt  = (unsigned short*)(ws + 0x1200000);
  unsigned short* X   = (unsigned short*)(ws + 0x1800000);   // also Vin (dead
                                                             // before X write)
  // bf16 input staging: Kin/Qin live in d_out (12.58 MB = exactly 2 buffers),
  // which is not written until gemm2.
  unsigned short* Kin = (unsigned short*)d_out;
  unsigned short* Qin = (unsigned short*)d_out + 3145728;
  unsigned short* Vin = X;
  float* out = (float*)d_out;

  conv_pack_kernel<<<dim3(12544), dim3(256), 0, stream>>>(
      Wk, Wq, Wv, Wc, key, query, value, mask,
      Wkb, Wqb, Wvb, Wcb, Kin, Qin, Vin, mbits);
  gemm_qkv_kernel<<<dim3(32, 6, 3), dim3(256), 0, stream>>>(
      Qin, Kin, Vin, Wqb, Wkb, Wvb, bq, bk, bv, Qb, Kb, Vt);
  attn_kernel<<<dim3(768), dim3(256), 0, stream>>>(Qb, Kb, Vt, mbits, X);
  gemm2_kernel<<<dim3(64, 6), dim3(256), 0, stream>>>(X, Wcb, bc, query, out);
  ln_kernel<<<dim3(1024), dim3(256), 0, stream>>>(out, lng, lnb);
}